// Round 1
// baseline (474.069 us; speedup 1.0000x reference)
//
#include <hip/hip_runtime.h>

#define NN 50000
#define EE 800000
#define TE (EE + NN)   // total edges including self loops

__device__ __forceinline__ float lrelu(float v){ return v > 0.f ? v : 0.2f*v; }

// ---------------- CSR build ----------------
__global__ __launch_bounds__(256) void k_init_deg(int* __restrict__ deg){
  int i = blockIdx.x*256 + threadIdx.x;
  if (i < NN) deg[i] = 1;                 // self loop
}

__global__ __launch_bounds__(256) void k_hist(const int* __restrict__ ei, int* __restrict__ deg){
  int e = blockIdx.x*256 + threadIdx.x;
  if (e < EE) atomicAdd(&deg[ei[EE + e]], 1);
}

__global__ __launch_bounds__(1024) void k_scan(const int* __restrict__ deg,
                                               int* __restrict__ rowptr,
                                               int* __restrict__ cursor){
  __shared__ int sums[1024];
  int tid = threadIdx.x;
  const int chunk = (NN + 1023)/1024;     // 49
  int start = tid*chunk; if (start > NN) start = NN;
  int end = start + chunk; if (end > NN) end = NN;
  int s = 0;
  for (int i = start; i < end; ++i) s += deg[i];
  sums[tid] = s;
  __syncthreads();
  for (int off = 1; off < 1024; off <<= 1){
    int add = (tid >= off) ? sums[tid-off] : 0;
    __syncthreads();
    sums[tid] += add;
    __syncthreads();
  }
  int offv = (tid > 0) ? sums[tid-1] : 0;
  for (int i = start; i < end; ++i){
    rowptr[i] = offv; cursor[i] = offv; offv += deg[i];
  }
  if (tid == 1023) rowptr[NN] = offv;     // == TE
}

__global__ __launch_bounds__(256) void k_scatter(const int* __restrict__ ei,
                                                 int* __restrict__ cursor,
                                                 int* __restrict__ csr_src){
  int idx = blockIdx.x*256 + threadIdx.x;
  if (idx >= TE) return;
  int s, d;
  if (idx < EE){ s = ei[idx]; d = ei[EE + idx]; }
  else { s = idx - EE; d = s; }
  int pos = atomicAdd(&cursor[d], 1);
  csr_src[pos] = s;
}

// ---------------- GEMM1: h1 = x @ W1  (+ fused attention dots) ----------------
__global__ __launch_bounds__(256) void k_gemm1(const float* __restrict__ x, const float* __restrict__ W,
    const float* __restrict__ a_src, const float* __restrict__ a_dst,
    float* __restrict__ h1, float* __restrict__ al_s, float* __restrict__ al_d){
  __shared__ float Ws[128*128];   // 64 KB
  __shared__ float xs[32*128];    // 16 KB
  int tid = threadIdx.x;
  const float4* W4 = (const float4*)W;
  float4* Ws4 = (float4*)Ws;
  #pragma unroll
  for (int i = 0; i < 16; ++i) Ws4[tid + i*256] = W4[tid + i*256];
  int row0 = blockIdx.x * 32;
  const float4* x4 = (const float4*)(x + (size_t)row0*128);
  float4* xs4 = (float4*)xs;
  for (int i = tid; i < 1024; i += 256){
    int r = i >> 5;
    xs4[i] = (row0 + r < NN) ? x4[i] : make_float4(0.f,0.f,0.f,0.f);
  }
  __syncthreads();
  int r  = tid >> 3;          // 0..31
  int c0 = (tid & 7) << 4;    // 0..112, 16 cols each (within one head)
  float acc[16];
  #pragma unroll
  for (int j = 0; j < 16; ++j) acc[j] = 0.f;
  for (int k = 0; k < 128; ++k){
    float xv = xs[r*128 + k];
    const float4* wr = (const float4*)(Ws + k*128 + c0);
    float4 w0 = wr[0], w1 = wr[1], w2 = wr[2], w3 = wr[3];
    acc[0]  += xv*w0.x; acc[1]  += xv*w0.y; acc[2]  += xv*w0.z; acc[3]  += xv*w0.w;
    acc[4]  += xv*w1.x; acc[5]  += xv*w1.y; acc[6]  += xv*w1.z; acc[7]  += xv*w1.w;
    acc[8]  += xv*w2.x; acc[9]  += xv*w2.y; acc[10] += xv*w2.z; acc[11] += xv*w2.w;
    acc[12] += xv*w3.x; acc[13] += xv*w3.y; acc[14] += xv*w3.z; acc[15] += xv*w3.w;
  }
  int n = row0 + r;
  int h = c0 >> 5;
  int cb = c0 & 31;
  float ps = 0.f, pd = 0.f;
  #pragma unroll
  for (int j = 0; j < 16; ++j){
    ps += acc[j] * a_src[h*32 + cb + j];
    pd += acc[j] * a_dst[h*32 + cb + j];
  }
  ps += __shfl_xor(ps, 1);    // pair (tid, tid^1) shares (row, head)
  pd += __shfl_xor(pd, 1);
  if (n < NN){
    float4* o = (float4*)(h1 + (size_t)n*128 + c0);
    o[0] = make_float4(acc[0],acc[1],acc[2],acc[3]);
    o[1] = make_float4(acc[4],acc[5],acc[6],acc[7]);
    o[2] = make_float4(acc[8],acc[9],acc[10],acc[11]);
    o[3] = make_float4(acc[12],acc[13],acc[14],acc[15]);
    if ((tid & 1) == 0){ al_s[n*4 + h] = ps; al_d[n*4 + h] = pd; }
  }
}

// ---------------- layer-1 aggregation: softmax over incoming edges + ELU ----------------
__global__ __launch_bounds__(256) void k_agg1(const int* __restrict__ rowptr, const int* __restrict__ csr_src,
    const float* __restrict__ h1, const float* __restrict__ al_s, const float* __restrict__ al_d,
    const float* __restrict__ b1, float* __restrict__ h2){
  int wid  = (blockIdx.x*256 + threadIdx.x) >> 6;   // node id
  int lane = threadIdx.x & 63;
  if (wid >= NN) return;
  int d = wid;
  int h0 = lane >> 5;         // head of channel `lane`      (0..1)
  int h1i = 2 + (lane >> 5);  // head of channel `lane+64`   (2..3)
  float ad0 = al_d[d*4 + h0];
  float ad1 = al_d[d*4 + h1i];
  int rs = rowptr[d], re = rowptr[d+1];
  float acc0 = 0.f, acc1 = 0.f, den0 = 0.f, den1 = 0.f;
  for (int i = rs; i < re; ++i){
    int s = csr_src[i];
    float e0 = lrelu(al_s[s*4 + h0]  + ad0);
    float e1 = lrelu(al_s[s*4 + h1i] + ad1);
    float ex0 = __expf(e0), ex1 = __expf(e1);   // no max-subtraction: |e| <= ~8, safe in fp32
    den0 += ex0; den1 += ex1;
    float v0 = h1[(size_t)s*128 + lane];
    float v1 = h1[(size_t)s*128 + 64 + lane];
    acc0 += ex0*v0; acc1 += ex1*v1;
  }
  float o0 = acc0/(den0 + 1e-16f) + b1[lane];
  float o1 = acc1/(den1 + 1e-16f) + b1[64 + lane];
  o0 = o0 > 0.f ? o0 : (__expf(o0) - 1.f);      // ELU fused
  o1 = o1 > 0.f ? o1 : (__expf(o1) - 1.f);
  h2[(size_t)d*128 + lane] = o0;
  h2[(size_t)d*128 + 64 + lane] = o1;
}

// ---------------- GEMM2: g = h2 @ W2  (+ fused attention dots, H=1) ----------------
__global__ __launch_bounds__(256) void k_gemm2(const float* __restrict__ h2, const float* __restrict__ W,
    const float* __restrict__ a_src, const float* __restrict__ a_dst,
    float* __restrict__ g, float* __restrict__ al_s, float* __restrict__ al_d){
  __shared__ float Ws[128*64];    // 32 KB
  __shared__ float xs[32*128];    // 16 KB
  int tid = threadIdx.x;
  const float4* W4 = (const float4*)W;
  float4* Ws4 = (float4*)Ws;
  #pragma unroll
  for (int i = 0; i < 8; ++i) Ws4[tid + i*256] = W4[tid + i*256];
  int row0 = blockIdx.x * 32;
  const float4* x4 = (const float4*)(h2 + (size_t)row0*128);
  float4* xs4 = (float4*)xs;
  for (int i = tid; i < 1024; i += 256){
    int r = i >> 5;
    xs4[i] = (row0 + r < NN) ? x4[i] : make_float4(0.f,0.f,0.f,0.f);
  }
  __syncthreads();
  int r  = tid >> 3;          // 0..31
  int c0 = (tid & 7) << 3;    // 0..56, 8 cols each
  float acc[8];
  #pragma unroll
  for (int j = 0; j < 8; ++j) acc[j] = 0.f;
  for (int k = 0; k < 128; ++k){
    float xv = xs[r*128 + k];
    const float4* wr = (const float4*)(Ws + k*64 + c0);
    float4 w0 = wr[0], w1 = wr[1];
    acc[0] += xv*w0.x; acc[1] += xv*w0.y; acc[2] += xv*w0.z; acc[3] += xv*w0.w;
    acc[4] += xv*w1.x; acc[5] += xv*w1.y; acc[6] += xv*w1.z; acc[7] += xv*w1.w;
  }
  int n = row0 + r;
  float ps = 0.f, pd = 0.f;
  #pragma unroll
  for (int j = 0; j < 8; ++j){
    ps += acc[j]*a_src[c0 + j];
    pd += acc[j]*a_dst[c0 + j];
  }
  ps += __shfl_xor(ps,1); pd += __shfl_xor(pd,1);
  ps += __shfl_xor(ps,2); pd += __shfl_xor(pd,2);
  ps += __shfl_xor(ps,4); pd += __shfl_xor(pd,4);
  if (n < NN){
    float4* o = (float4*)(g + (size_t)n*64 + c0);
    o[0] = make_float4(acc[0],acc[1],acc[2],acc[3]);
    o[1] = make_float4(acc[4],acc[5],acc[6],acc[7]);
    if ((tid & 7) == 0){ al_s[n] = ps; al_d[n] = pd; }
  }
}

// ---------------- layer-2 aggregation -> d_out ----------------
__global__ __launch_bounds__(256) void k_agg2(const int* __restrict__ rowptr, const int* __restrict__ csr_src,
    const float* __restrict__ g, const float* __restrict__ al_s, const float* __restrict__ al_d,
    const float* __restrict__ b2, float* __restrict__ out){
  int wid  = (blockIdx.x*256 + threadIdx.x) >> 6;   // node id
  int lane = threadIdx.x & 63;                      // channel (0..63)
  if (wid >= NN) return;
  int d = wid;
  float ad = al_d[d];
  int rs = rowptr[d], re = rowptr[d+1];
  float acc = 0.f, den = 0.f;
  for (int i = rs; i < re; ++i){
    int s = csr_src[i];
    float e = lrelu(al_s[s] + ad);
    float ex = __expf(e);
    den += ex;
    acc += ex * g[(size_t)s*64 + lane];
  }
  out[(size_t)d*64 + lane] = acc/(den + 1e-16f) + b2[lane];
}

extern "C" void kernel_launch(void* const* d_in, const int* in_sizes, int n_in,
                              void* d_out, int out_size, void* d_ws, size_t ws_size,
                              hipStream_t stream){
  const float* x   = (const float*)d_in[0];
  const int*   ei  = (const int*)d_in[1];
  const float* W1  = (const float*)d_in[2];
  const float* as1 = (const float*)d_in[3];
  const float* ad1 = (const float*)d_in[4];
  const float* b1  = (const float*)d_in[5];
  const float* W2  = (const float*)d_in[6];
  const float* as2 = (const float*)d_in[7];
  const float* ad2 = (const float*)d_in[8];
  const float* b2  = (const float*)d_in[9];
  float* out = (float*)d_out;
  (void)in_sizes; (void)n_in; (void)out_size; (void)ws_size;

  char* p = (char*)d_ws;
  size_t off = 0;
  auto alloc = [&](size_t bytes)->char*{
    char* r = p + off; off += (bytes + 255) & ~size_t(255); return r;
  };
  float* h1    = (float*)alloc((size_t)NN*128*4);
  float* h2    = (float*)alloc((size_t)NN*128*4);
  float* g     = (float*)alloc((size_t)NN*64*4);
  float* al1s  = (float*)alloc((size_t)NN*4*4);
  float* al1d  = (float*)alloc((size_t)NN*4*4);
  float* al2s  = (float*)alloc((size_t)NN*4);
  float* al2d  = (float*)alloc((size_t)NN*4);
  int*   deg   = (int*)alloc((size_t)NN*4);
  int*   rowptr= (int*)alloc((size_t)(NN+1)*4);
  int*   cursor= (int*)alloc((size_t)NN*4);
  int*   csr   = (int*)alloc((size_t)TE*4);

  k_init_deg<<<(NN+255)/256, 256, 0, stream>>>(deg);
  k_hist<<<(EE+255)/256, 256, 0, stream>>>(ei, deg);
  k_scan<<<1, 1024, 0, stream>>>(deg, rowptr, cursor);
  k_scatter<<<(TE+255)/256, 256, 0, stream>>>(ei, cursor, csr);
  k_gemm1<<<(NN+31)/32, 256, 0, stream>>>(x, W1, as1, ad1, h1, al1s, al1d);
  k_agg1<<<(NN+3)/4, 256, 0, stream>>>(rowptr, csr, h1, al1s, al1d, b1, h2);
  k_gemm2<<<(NN+31)/32, 256, 0, stream>>>(h2, W2, as2, ad2, g, al2s, al2d);
  k_agg2<<<(NN+3)/4, 256, 0, stream>>>(rowptr, csr, g, al2s, al2d, b2, out);
}

// Round 2
// 338.653 us; speedup vs baseline: 1.3999x; 1.3999x over previous
//
#include <hip/hip_runtime.h>

#define NN 50000
#define EE 800000
#define TE (EE + NN)     // total edges including self loops
#define SCAN_B 196       // ceil(NN/256)

__device__ __forceinline__ float lrelu(float v){ return v > 0.f ? v : 0.2f*v; }

// ---------------- CSR build ----------------
__global__ __launch_bounds__(256) void k_init_deg(int* __restrict__ deg){
  int i = blockIdx.x*256 + threadIdx.x;
  if (i < NN) deg[i] = 1;                 // self loop
}

__global__ __launch_bounds__(256) void k_hist(const int* __restrict__ ei, int* __restrict__ deg){
  int e = blockIdx.x*256 + threadIdx.x;
  if (e < EE) atomicAdd(&deg[ei[EE + e]], 1);
}

// block sums of deg (256 elems per block)
__global__ __launch_bounds__(256) void k_bsum(const int* __restrict__ deg, int* __restrict__ bsum){
  __shared__ int red[256];
  int t = threadIdx.x;
  int i = blockIdx.x*256 + t;
  red[t] = (i < NN) ? deg[i] : 0;
  __syncthreads();
  for (int off = 128; off > 0; off >>= 1){
    if (t < off) red[t] += red[t+off];
    __syncthreads();
  }
  if (t == 0) bsum[blockIdx.x] = red[0];
}

// single-block exclusive scan of the 196 block sums
__global__ __launch_bounds__(256) void k_bscan(const int* __restrict__ bsum, int* __restrict__ boff){
  __shared__ int s[256];
  int t = threadIdx.x;
  int v = (t < SCAN_B) ? bsum[t] : 0;
  s[t] = v;
  __syncthreads();
  for (int off = 1; off < 256; off <<= 1){
    int add = (t >= off) ? s[t-off] : 0;
    __syncthreads();
    s[t] += add;
    __syncthreads();
  }
  if (t < SCAN_B) boff[t] = s[t] - v;   // exclusive
}

// per-block local scan + block offset -> rowptr/cursor
__global__ __launch_bounds__(256) void k_final(const int* __restrict__ deg, const int* __restrict__ boff,
                                               int* __restrict__ rowptr, int* __restrict__ cursor){
  __shared__ int s[256];
  int t = threadIdx.x;
  int i = blockIdx.x*256 + t;
  int v = (i < NN) ? deg[i] : 0;
  s[t] = v;
  __syncthreads();
  for (int off = 1; off < 256; off <<= 1){
    int add = (t >= off) ? s[t-off] : 0;
    __syncthreads();
    s[t] += add;
    __syncthreads();
  }
  if (i < NN){
    int ex = boff[blockIdx.x] + s[t] - v;
    rowptr[i] = ex;
    cursor[i] = ex;
  }
  if (i == 0) rowptr[NN] = TE;
}

__global__ __launch_bounds__(256) void k_scatter(const int* __restrict__ ei,
                                                 int* __restrict__ cursor,
                                                 int* __restrict__ csr_src){
  int idx = blockIdx.x*256 + threadIdx.x;
  if (idx >= TE) return;
  int s, d;
  if (idx < EE){ s = ei[idx]; d = ei[EE + idx]; }
  else { s = idx - EE; d = s; }
  int pos = atomicAdd(&cursor[d], 1);
  csr_src[pos] = s;
}

// ---------------- GEMM1: h1 = x @ W1 (+ fused attention dots) ----------------
// 256 thr, 128 rows/block, 4 rows x 16 cols per thread, K split in 2 halves of 64.
// cols per thread: cg*4 + 32*jc (+q), jc = head. Conflict-free LDS.
__global__ __launch_bounds__(256) void k_gemm1(const float* __restrict__ x, const float* __restrict__ W,
    const float* __restrict__ a_src, const float* __restrict__ a_dst,
    float* __restrict__ h1, float* __restrict__ al_s, float* __restrict__ al_d){
  __shared__ float Ws[64*128];      // 32 KB (one K-half)
  __shared__ float xs[128*68];      // 34 KB, stride 68 (16B aligned, bank-spread)
  int tid = threadIdx.x;
  int row0 = blockIdx.x * 128;
  int rg = tid >> 3;                // 0..31
  int cg = tid & 7;                 // 0..7
  float acc[64];                    // [jr][jc*4+q]
  #pragma unroll
  for (int i = 0; i < 64; ++i) acc[i] = 0.f;
  const float4* W4 = (const float4*)W;
  const float4* x4 = (const float4*)x;
  float4* Ws4 = (float4*)Ws;

  for (int kh = 0; kh < 2; ++kh){
    if (kh) __syncthreads();
    #pragma unroll
    for (int f0 = 0; f0 < 2048; f0 += 256){
      int f = f0 + tid;
      Ws4[f] = W4[kh*2048 + f];     // W half is contiguous [64][128]
    }
    #pragma unroll
    for (int f0 = 0; f0 < 2048; f0 += 256){
      int f = f0 + tid;
      int row = f >> 4, kq = f & 15;
      float4 v = make_float4(0.f,0.f,0.f,0.f);
      if (row0 + row < NN) v = x4[(size_t)(row0+row)*32 + kh*16 + kq];
      *(float4*)(xs + row*68 + kq*4) = v;
    }
    __syncthreads();

    #pragma unroll 4
    for (int k = 0; k < 64; ++k){
      float xv0 = xs[(rg     )*68 + k];
      float xv1 = xs[(rg + 32)*68 + k];
      float xv2 = xs[(rg + 64)*68 + k];
      float xv3 = xs[(rg + 96)*68 + k];
      const float4* wr = (const float4*)(Ws + k*128);
      float4 w0 = wr[cg], w1 = wr[cg+8], w2 = wr[cg+16], w3 = wr[cg+24];
      #define FMA_ROW(jr, xv) \
        acc[jr*16+ 0] += xv*w0.x; acc[jr*16+ 1] += xv*w0.y; acc[jr*16+ 2] += xv*w0.z; acc[jr*16+ 3] += xv*w0.w; \
        acc[jr*16+ 4] += xv*w1.x; acc[jr*16+ 5] += xv*w1.y; acc[jr*16+ 6] += xv*w1.z; acc[jr*16+ 7] += xv*w1.w; \
        acc[jr*16+ 8] += xv*w2.x; acc[jr*16+ 9] += xv*w2.y; acc[jr*16+10] += xv*w2.z; acc[jr*16+11] += xv*w2.w; \
        acc[jr*16+12] += xv*w3.x; acc[jr*16+13] += xv*w3.y; acc[jr*16+14] += xv*w3.z; acc[jr*16+15] += xv*w3.w;
      FMA_ROW(0, xv0) FMA_ROW(1, xv1) FMA_ROW(2, xv2) FMA_ROW(3, xv3)
      #undef FMA_ROW
    }
  }

  // epilogue
  #pragma unroll
  for (int jr = 0; jr < 4; ++jr){
    int n = row0 + rg + 32*jr;
    bool ok = (n < NN);
    float4* o = (float4*)(h1 + (size_t)n*128 + cg*4);
    #pragma unroll
    for (int jc = 0; jc < 4; ++jc){
      float4 v = make_float4(acc[jr*16+jc*4], acc[jr*16+jc*4+1], acc[jr*16+jc*4+2], acc[jr*16+jc*4+3]);
      if (ok) o[jc*8] = v;          // +32 floats per jc
      int ab = jc*32 + cg*4;
      float ps = v.x*a_src[ab] + v.y*a_src[ab+1] + v.z*a_src[ab+2] + v.w*a_src[ab+3];
      float pd = v.x*a_dst[ab] + v.y*a_dst[ab+1] + v.z*a_dst[ab+2] + v.w*a_dst[ab+3];
      ps += __shfl_xor(ps, 1); ps += __shfl_xor(ps, 2); ps += __shfl_xor(ps, 4);
      pd += __shfl_xor(pd, 1); pd += __shfl_xor(pd, 2); pd += __shfl_xor(pd, 4);
      if (ok && cg == 0){ al_s[n*4 + jc] = ps; al_d[n*4 + jc] = pd; }
    }
  }
}

// ---------------- layer-1 aggregation (softmax + ELU), float2 per lane ----------------
__global__ __launch_bounds__(256) void k_agg1(const int* __restrict__ rowptr, const int* __restrict__ csr_src,
    const float* __restrict__ h1v, const float* __restrict__ al_s, const float* __restrict__ al_d,
    const float* __restrict__ b1, float* __restrict__ h2){
  int wid  = (blockIdx.x*256 + threadIdx.x) >> 6;   // node id
  int lane = threadIdx.x & 63;
  if (wid >= NN) return;
  int h = lane >> 4;                                // channels (2*lane, 2*lane+1) share head
  float ad = al_d[wid*4 + h];
  int rs = rowptr[wid], re = rowptr[wid+1];
  float accx = 0.f, accy = 0.f, den = 0.f;
  for (int i = rs; i < re; ++i){
    int s = csr_src[i];
    float e = lrelu(al_s[s*4 + h] + ad);
    float ex = __expf(e);                           // no max-sub: |e| <= ~8, safe fp32
    den += ex;
    float2 v = *(const float2*)(h1v + (size_t)s*128 + lane*2);
    accx += ex*v.x; accy += ex*v.y;
  }
  float inv = 1.f/(den + 1e-16f);
  float2 bb = *(const float2*)(b1 + lane*2);
  float o0 = accx*inv + bb.x;
  float o1 = accy*inv + bb.y;
  o0 = o0 > 0.f ? o0 : (__expf(o0) - 1.f);          // ELU fused
  o1 = o1 > 0.f ? o1 : (__expf(o1) - 1.f);
  *(float2*)(h2 + (size_t)wid*128 + lane*2) = make_float2(o0, o1);
}

// ---------------- GEMM2: g = h2 @ W2 (+ fused attention dots, H=1) ----------------
// 256 thr, 128 rows/block, 4 rows x 8 cols per thread, K split in 2 halves of 64.
__global__ __launch_bounds__(256) void k_gemm2(const float* __restrict__ h2, const float* __restrict__ W,
    const float* __restrict__ a_src, const float* __restrict__ a_dst,
    float* __restrict__ g, float* __restrict__ al_s, float* __restrict__ al_d){
  __shared__ float Ws[64*64];       // 16 KB (one K-half)
  __shared__ float xs[128*68];      // 34 KB
  int tid = threadIdx.x;
  int row0 = blockIdx.x * 128;
  int rg = tid >> 3;
  int cg = tid & 7;
  float acc[32];                    // [jr][jc*4+q], jc in {0,1}
  #pragma unroll
  for (int i = 0; i < 32; ++i) acc[i] = 0.f;
  const float4* W4 = (const float4*)W;
  const float4* x4 = (const float4*)h2;
  float4* Ws4 = (float4*)Ws;

  for (int kh = 0; kh < 2; ++kh){
    if (kh) __syncthreads();
    #pragma unroll
    for (int f0 = 0; f0 < 1024; f0 += 256){
      int f = f0 + tid;
      Ws4[f] = W4[kh*1024 + f];     // W2 half contiguous [64][64]
    }
    #pragma unroll
    for (int f0 = 0; f0 < 2048; f0 += 256){
      int f = f0 + tid;
      int row = f >> 4, kq = f & 15;
      float4 v = make_float4(0.f,0.f,0.f,0.f);
      if (row0 + row < NN) v = x4[(size_t)(row0+row)*32 + kh*16 + kq];
      *(float4*)(xs + row*68 + kq*4) = v;
    }
    __syncthreads();

    #pragma unroll 4
    for (int k = 0; k < 64; ++k){
      float xv0 = xs[(rg     )*68 + k];
      float xv1 = xs[(rg + 32)*68 + k];
      float xv2 = xs[(rg + 64)*68 + k];
      float xv3 = xs[(rg + 96)*68 + k];
      const float4* wr = (const float4*)(Ws + k*64);
      float4 w0 = wr[cg], w1 = wr[cg+8];
      #define FMA_ROW2(jr, xv) \
        acc[jr*8+0] += xv*w0.x; acc[jr*8+1] += xv*w0.y; acc[jr*8+2] += xv*w0.z; acc[jr*8+3] += xv*w0.w; \
        acc[jr*8+4] += xv*w1.x; acc[jr*8+5] += xv*w1.y; acc[jr*8+6] += xv*w1.z; acc[jr*8+7] += xv*w1.w;
      FMA_ROW2(0, xv0) FMA_ROW2(1, xv1) FMA_ROW2(2, xv2) FMA_ROW2(3, xv3)
      #undef FMA_ROW2
    }
  }

  #pragma unroll
  for (int jr = 0; jr < 4; ++jr){
    int n = row0 + rg + 32*jr;
    bool ok = (n < NN);
    float4 v0 = make_float4(acc[jr*8+0], acc[jr*8+1], acc[jr*8+2], acc[jr*8+3]);
    float4 v1 = make_float4(acc[jr*8+4], acc[jr*8+5], acc[jr*8+6], acc[jr*8+7]);
    if (ok){
      float4* o = (float4*)(g + (size_t)n*64 + cg*4);
      o[0] = v0;
      o[8] = v1;                    // +32 floats
    }
    int ab = cg*4;
    float ps = v0.x*a_src[ab] + v0.y*a_src[ab+1] + v0.z*a_src[ab+2] + v0.w*a_src[ab+3]
             + v1.x*a_src[32+ab] + v1.y*a_src[32+ab+1] + v1.z*a_src[32+ab+2] + v1.w*a_src[32+ab+3];
    float pd = v0.x*a_dst[ab] + v0.y*a_dst[ab+1] + v0.z*a_dst[ab+2] + v0.w*a_dst[ab+3]
             + v1.x*a_dst[32+ab] + v1.y*a_dst[32+ab+1] + v1.z*a_dst[32+ab+2] + v1.w*a_dst[32+ab+3];
    ps += __shfl_xor(ps, 1); ps += __shfl_xor(ps, 2); ps += __shfl_xor(ps, 4);
    pd += __shfl_xor(pd, 1); pd += __shfl_xor(pd, 2); pd += __shfl_xor(pd, 4);
    if (ok && cg == 0){ al_s[n] = ps; al_d[n] = pd; }
  }
}

// ---------------- layer-2 aggregation -> d_out ----------------
__global__ __launch_bounds__(256) void k_agg2(const int* __restrict__ rowptr, const int* __restrict__ csr_src,
    const float* __restrict__ g, const float* __restrict__ al_s, const float* __restrict__ al_d,
    const float* __restrict__ b2, float* __restrict__ out){
  int wid  = (blockIdx.x*256 + threadIdx.x) >> 6;   // node id
  int lane = threadIdx.x & 63;                      // channel
  if (wid >= NN) return;
  float ad = al_d[wid];
  int rs = rowptr[wid], re = rowptr[wid+1];
  float acc = 0.f, den = 0.f;
  for (int i = rs; i < re; ++i){
    int s = csr_src[i];
    float e = lrelu(al_s[s] + ad);
    float ex = __expf(e);
    den += ex;
    acc += ex * g[(size_t)s*64 + lane];
  }
  out[(size_t)wid*64 + lane] = acc/(den + 1e-16f) + b2[lane];
}

extern "C" void kernel_launch(void* const* d_in, const int* in_sizes, int n_in,
                              void* d_out, int out_size, void* d_ws, size_t ws_size,
                              hipStream_t stream){
  const float* x   = (const float*)d_in[0];
  const int*   ei  = (const int*)d_in[1];
  const float* W1  = (const float*)d_in[2];
  const float* as1 = (const float*)d_in[3];
  const float* ad1 = (const float*)d_in[4];
  const float* b1  = (const float*)d_in[5];
  const float* W2  = (const float*)d_in[6];
  const float* as2 = (const float*)d_in[7];
  const float* ad2 = (const float*)d_in[8];
  const float* b2  = (const float*)d_in[9];
  float* out = (float*)d_out;
  (void)in_sizes; (void)n_in; (void)out_size; (void)ws_size;

  char* p = (char*)d_ws;
  size_t off = 0;
  auto alloc = [&](size_t bytes)->char*{
    char* r = p + off; off += (bytes + 255) & ~size_t(255); return r;
  };
  float* h1    = (float*)alloc((size_t)NN*128*4);
  float* h2    = (float*)alloc((size_t)NN*128*4);
  float* g     = (float*)alloc((size_t)NN*64*4);
  float* al1s  = (float*)alloc((size_t)NN*4*4);
  float* al1d  = (float*)alloc((size_t)NN*4*4);
  float* al2s  = (float*)alloc((size_t)NN*4);
  float* al2d  = (float*)alloc((size_t)NN*4);
  int*   deg   = (int*)alloc((size_t)NN*4);
  int*   rowptr= (int*)alloc((size_t)(NN+1)*4);
  int*   cursor= (int*)alloc((size_t)NN*4);
  int*   csr   = (int*)alloc((size_t)TE*4);
  int*   bsum  = (int*)alloc((size_t)SCAN_B*4);
  int*   boff  = (int*)alloc((size_t)SCAN_B*4);

  k_init_deg<<<SCAN_B, 256, 0, stream>>>(deg);
  k_hist<<<(EE+255)/256, 256, 0, stream>>>(ei, deg);
  k_bsum<<<SCAN_B, 256, 0, stream>>>(deg, bsum);
  k_bscan<<<1, 256, 0, stream>>>(bsum, boff);
  k_final<<<SCAN_B, 256, 0, stream>>>(deg, boff, rowptr, cursor);
  k_scatter<<<(TE+255)/256, 256, 0, stream>>>(ei, cursor, csr);
  k_gemm1<<<(NN+127)/128, 256, 0, stream>>>(x, W1, as1, ad1, h1, al1s, al1d);
  k_agg1<<<(NN*64+255)/256, 256, 0, stream>>>(rowptr, csr, h1, al1s, al1d, b1, h2);
  k_gemm2<<<(NN+127)/128, 256, 0, stream>>>(h2, W2, as2, ad2, g, al2s, al2d);
  k_agg2<<<(NN*64+255)/256, 256, 0, stream>>>(rowptr, csr, g, al2s, al2d, b2, out);
}

// Round 3
// 243.961 us; speedup vs baseline: 1.9432x; 1.3881x over previous
//
#include <hip/hip_runtime.h>

#define NN 50000
#define EE 800000
#define TE (EE + NN)     // total edges including self loops
#define SCAN_B 196       // ceil(NN/256)

typedef unsigned int uint;

__device__ __forceinline__ float lrelu(float v){ return v > 0.f ? v : 0.2f*v; }
// round-to-nearest-even fp32 -> bf16 (top 16 bits), packed pair (lo=a, hi=b)
__device__ __forceinline__ uint pack_bf16(float a, float b){
  uint ua = __float_as_uint(a), ub = __float_as_uint(b);
  ua = (ua + 0x7FFFu + ((ua >> 16) & 1u)) >> 16;
  ub = (ub + 0x7FFFu + ((ub >> 16) & 1u)) & 0xFFFF0000u;
  return ua | ub;
}
__device__ __forceinline__ float bf_lo(uint u){ return __uint_as_float(u << 16); }
__device__ __forceinline__ float bf_hi(uint u){ return __uint_as_float(u & 0xFFFF0000u); }

// ---------------- CSR build ----------------
__global__ __launch_bounds__(256) void k_init_deg(int* __restrict__ deg){
  int i = blockIdx.x*256 + threadIdx.x;
  if (i < NN) deg[i] = 1;                 // self loop
}

__global__ __launch_bounds__(256) void k_hist(const int* __restrict__ ei, int* __restrict__ deg){
  int e = blockIdx.x*256 + threadIdx.x;
  if (e < EE) atomicAdd(&deg[ei[EE + e]], 1);
}

__global__ __launch_bounds__(256) void k_bsum(const int* __restrict__ deg, int* __restrict__ bsum){
  __shared__ int red[256];
  int t = threadIdx.x;
  int i = blockIdx.x*256 + t;
  red[t] = (i < NN) ? deg[i] : 0;
  __syncthreads();
  for (int off = 128; off > 0; off >>= 1){
    if (t < off) red[t] += red[t+off];
    __syncthreads();
  }
  if (t == 0) bsum[blockIdx.x] = red[0];
}

__global__ __launch_bounds__(256) void k_bscan(const int* __restrict__ bsum, int* __restrict__ boff){
  __shared__ int s[256];
  int t = threadIdx.x;
  int v = (t < SCAN_B) ? bsum[t] : 0;
  s[t] = v;
  __syncthreads();
  for (int off = 1; off < 256; off <<= 1){
    int add = (t >= off) ? s[t-off] : 0;
    __syncthreads();
    s[t] += add;
    __syncthreads();
  }
  if (t < SCAN_B) boff[t] = s[t] - v;   // exclusive
}

__global__ __launch_bounds__(256) void k_final(const int* __restrict__ deg, const int* __restrict__ boff,
                                               int* __restrict__ rowptr, int* __restrict__ cursor){
  __shared__ int s[256];
  int t = threadIdx.x;
  int i = blockIdx.x*256 + t;
  int v = (i < NN) ? deg[i] : 0;
  s[t] = v;
  __syncthreads();
  for (int off = 1; off < 256; off <<= 1){
    int add = (t >= off) ? s[t-off] : 0;
    __syncthreads();
    s[t] += add;
    __syncthreads();
  }
  if (i < NN){
    int ex = boff[blockIdx.x] + s[t] - v;
    rowptr[i] = ex;
    cursor[i] = ex;
  }
  if (i == 0) rowptr[NN] = TE;
}

__global__ __launch_bounds__(256) void k_scatter(const int* __restrict__ ei,
                                                 int* __restrict__ cursor,
                                                 int* __restrict__ csr_src){
  int idx = blockIdx.x*256 + threadIdx.x;
  if (idx >= TE) return;
  int s, d;
  if (idx < EE){ s = ei[idx]; d = ei[EE + idx]; }
  else { s = idx - EE; d = s; }
  int pos = atomicAdd(&cursor[d], 1);
  csr_src[pos] = s;
}

// ---------------- GEMM1: h1 = x @ W1 (+ fused attention dots), bf16 output ----------------
__global__ __launch_bounds__(256) void k_gemm1(const float* __restrict__ x, const float* __restrict__ W,
    const float* __restrict__ a_src, const float* __restrict__ a_dst,
    uint* __restrict__ h1b, float* __restrict__ al_s, float* __restrict__ al_d){
  __shared__ float Ws[64*128];      // 32 KB (one K-half)
  __shared__ float xs[128*68];      // 34 KB, stride 68
  int tid = threadIdx.x;
  int row0 = blockIdx.x * 128;
  int rg = tid >> 3;                // 0..31
  int cg = tid & 7;                 // 0..7
  float acc[64];
  #pragma unroll
  for (int i = 0; i < 64; ++i) acc[i] = 0.f;
  const float4* W4 = (const float4*)W;
  const float4* x4 = (const float4*)x;
  float4* Ws4 = (float4*)Ws;

  for (int kh = 0; kh < 2; ++kh){
    if (kh) __syncthreads();
    #pragma unroll
    for (int f0 = 0; f0 < 2048; f0 += 256){
      int f = f0 + tid;
      Ws4[f] = W4[kh*2048 + f];
    }
    #pragma unroll
    for (int f0 = 0; f0 < 2048; f0 += 256){
      int f = f0 + tid;
      int row = f >> 4, kq = f & 15;
      float4 v = make_float4(0.f,0.f,0.f,0.f);
      if (row0 + row < NN) v = x4[(size_t)(row0+row)*32 + kh*16 + kq];
      *(float4*)(xs + row*68 + kq*4) = v;
    }
    __syncthreads();

    #pragma unroll 4
    for (int k = 0; k < 64; ++k){
      float xv0 = xs[(rg     )*68 + k];
      float xv1 = xs[(rg + 32)*68 + k];
      float xv2 = xs[(rg + 64)*68 + k];
      float xv3 = xs[(rg + 96)*68 + k];
      const float4* wr = (const float4*)(Ws + k*128);
      float4 w0 = wr[cg], w1 = wr[cg+8], w2 = wr[cg+16], w3 = wr[cg+24];
      #define FMA_ROW(jr, xv) \
        acc[jr*16+ 0] += xv*w0.x; acc[jr*16+ 1] += xv*w0.y; acc[jr*16+ 2] += xv*w0.z; acc[jr*16+ 3] += xv*w0.w; \
        acc[jr*16+ 4] += xv*w1.x; acc[jr*16+ 5] += xv*w1.y; acc[jr*16+ 6] += xv*w1.z; acc[jr*16+ 7] += xv*w1.w; \
        acc[jr*16+ 8] += xv*w2.x; acc[jr*16+ 9] += xv*w2.y; acc[jr*16+10] += xv*w2.z; acc[jr*16+11] += xv*w2.w; \
        acc[jr*16+12] += xv*w3.x; acc[jr*16+13] += xv*w3.y; acc[jr*16+14] += xv*w3.z; acc[jr*16+15] += xv*w3.w;
      FMA_ROW(0, xv0) FMA_ROW(1, xv1) FMA_ROW(2, xv2) FMA_ROW(3, xv3)
      #undef FMA_ROW
    }
  }

  #pragma unroll
  for (int jr = 0; jr < 4; ++jr){
    int n = row0 + rg + 32*jr;
    bool ok = (n < NN);
    uint* orow = h1b + (size_t)n*64;
    #pragma unroll
    for (int jc = 0; jc < 4; ++jc){
      float4 v = make_float4(acc[jr*16+jc*4], acc[jr*16+jc*4+1], acc[jr*16+jc*4+2], acc[jr*16+jc*4+3]);
      if (ok){
        uint2 pv = make_uint2(pack_bf16(v.x, v.y), pack_bf16(v.z, v.w));
        *(uint2*)(orow + jc*16 + cg*2) = pv;     // channels jc*32+cg*4 .. +3
      }
      int ab = jc*32 + cg*4;
      float ps = v.x*a_src[ab] + v.y*a_src[ab+1] + v.z*a_src[ab+2] + v.w*a_src[ab+3];
      float pd = v.x*a_dst[ab] + v.y*a_dst[ab+1] + v.z*a_dst[ab+2] + v.w*a_dst[ab+3];
      ps += __shfl_xor(ps, 1); ps += __shfl_xor(ps, 2); ps += __shfl_xor(ps, 4);
      pd += __shfl_xor(pd, 1); pd += __shfl_xor(pd, 2); pd += __shfl_xor(pd, 4);
      if (ok && cg == 0){ al_s[n*4 + jc] = ps; al_d[n*4 + jc] = pd; }
    }
  }
}

// ---------------- layer-1 aggregation (softmax + ELU), bf16 rows, 4x unrolled ----------------
__global__ __launch_bounds__(256) void k_agg1(const int* __restrict__ rowptr, const int* __restrict__ csr,
    const uint* __restrict__ h1b, const float* __restrict__ al_s, const float* __restrict__ al_d,
    const float* __restrict__ b1, float* __restrict__ h2){
  int wid  = (blockIdx.x*256 + threadIdx.x) >> 6;   // node id
  int lane = threadIdx.x & 63;
  if (wid >= NN) return;
  int h = lane >> 4;                  // channels (2*lane, 2*lane+1) share head
  float ad = al_d[wid*4 + h];
  int rs = rowptr[wid], re = rowptr[wid+1];
  float accx = 0.f, accy = 0.f, den = 0.f;
  int i = rs;
  for (; i + 4 <= re; i += 4){
    int s0 = csr[i], s1 = csr[i+1], s2 = csr[i+2], s3 = csr[i+3];
    float e0 = al_s[s0*4+h], e1 = al_s[s1*4+h], e2 = al_s[s2*4+h], e3 = al_s[s3*4+h];
    uint u0 = h1b[(size_t)s0*64 + lane];
    uint u1 = h1b[(size_t)s1*64 + lane];
    uint u2 = h1b[(size_t)s2*64 + lane];
    uint u3 = h1b[(size_t)s3*64 + lane];
    float ex0 = __expf(lrelu(e0 + ad));
    float ex1 = __expf(lrelu(e1 + ad));
    float ex2 = __expf(lrelu(e2 + ad));
    float ex3 = __expf(lrelu(e3 + ad));
    den  += ex0 + ex1 + ex2 + ex3;
    accx += ex0*bf_lo(u0) + ex1*bf_lo(u1) + ex2*bf_lo(u2) + ex3*bf_lo(u3);
    accy += ex0*bf_hi(u0) + ex1*bf_hi(u1) + ex2*bf_hi(u2) + ex3*bf_hi(u3);
  }
  for (; i < re; ++i){
    int s = csr[i];
    float ex = __expf(lrelu(al_s[s*4+h] + ad));
    uint u = h1b[(size_t)s*64 + lane];
    den += ex;
    accx += ex*bf_lo(u); accy += ex*bf_hi(u);
  }
  float inv = 1.f/(den + 1e-16f);
  float2 bb = *(const float2*)(b1 + lane*2);
  float o0 = accx*inv + bb.x;
  float o1 = accy*inv + bb.y;
  o0 = o0 > 0.f ? o0 : (__expf(o0) - 1.f);          // ELU fused
  o1 = o1 > 0.f ? o1 : (__expf(o1) - 1.f);
  *(float2*)(h2 + (size_t)wid*128 + lane*2) = make_float2(o0, o1);
}

// ---------------- GEMM2: g = h2 @ W2 (+ fused attention dots), bf16 output ----------------
__global__ __launch_bounds__(256) void k_gemm2(const float* __restrict__ h2, const float* __restrict__ W,
    const float* __restrict__ a_src, const float* __restrict__ a_dst,
    uint* __restrict__ gb, float* __restrict__ al_s, float* __restrict__ al_d){
  __shared__ float Ws[64*64];       // 16 KB
  __shared__ float xs[128*68];      // 34 KB
  int tid = threadIdx.x;
  int row0 = blockIdx.x * 128;
  int rg = tid >> 3;
  int cg = tid & 7;
  float acc[32];
  #pragma unroll
  for (int i = 0; i < 32; ++i) acc[i] = 0.f;
  const float4* W4 = (const float4*)W;
  const float4* x4 = (const float4*)h2;
  float4* Ws4 = (float4*)Ws;

  for (int kh = 0; kh < 2; ++kh){
    if (kh) __syncthreads();
    #pragma unroll
    for (int f0 = 0; f0 < 1024; f0 += 256){
      int f = f0 + tid;
      Ws4[f] = W4[kh*1024 + f];
    }
    #pragma unroll
    for (int f0 = 0; f0 < 2048; f0 += 256){
      int f = f0 + tid;
      int row = f >> 4, kq = f & 15;
      float4 v = make_float4(0.f,0.f,0.f,0.f);
      if (row0 + row < NN) v = x4[(size_t)(row0+row)*32 + kh*16 + kq];
      *(float4*)(xs + row*68 + kq*4) = v;
    }
    __syncthreads();

    #pragma unroll 4
    for (int k = 0; k < 64; ++k){
      float xv0 = xs[(rg     )*68 + k];
      float xv1 = xs[(rg + 32)*68 + k];
      float xv2 = xs[(rg + 64)*68 + k];
      float xv3 = xs[(rg + 96)*68 + k];
      const float4* wr = (const float4*)(Ws + k*64);
      float4 w0 = wr[cg], w1 = wr[cg+8];
      #define FMA_ROW2(jr, xv) \
        acc[jr*8+0] += xv*w0.x; acc[jr*8+1] += xv*w0.y; acc[jr*8+2] += xv*w0.z; acc[jr*8+3] += xv*w0.w; \
        acc[jr*8+4] += xv*w1.x; acc[jr*8+5] += xv*w1.y; acc[jr*8+6] += xv*w1.z; acc[jr*8+7] += xv*w1.w;
      FMA_ROW2(0, xv0) FMA_ROW2(1, xv1) FMA_ROW2(2, xv2) FMA_ROW2(3, xv3)
      #undef FMA_ROW2
    }
  }

  #pragma unroll
  for (int jr = 0; jr < 4; ++jr){
    int n = row0 + rg + 32*jr;
    bool ok = (n < NN);
    float4 v0 = make_float4(acc[jr*8+0], acc[jr*8+1], acc[jr*8+2], acc[jr*8+3]);
    float4 v1 = make_float4(acc[jr*8+4], acc[jr*8+5], acc[jr*8+6], acc[jr*8+7]);
    if (ok){
      uint* orow = gb + (size_t)n*32;
      *(uint2*)(orow + cg*2)      = make_uint2(pack_bf16(v0.x, v0.y), pack_bf16(v0.z, v0.w));
      *(uint2*)(orow + 16 + cg*2) = make_uint2(pack_bf16(v1.x, v1.y), pack_bf16(v1.z, v1.w));
    }
    int ab = cg*4;
    float ps = v0.x*a_src[ab] + v0.y*a_src[ab+1] + v0.z*a_src[ab+2] + v0.w*a_src[ab+3]
             + v1.x*a_src[32+ab] + v1.y*a_src[32+ab+1] + v1.z*a_src[32+ab+2] + v1.w*a_src[32+ab+3];
    float pd = v0.x*a_dst[ab] + v0.y*a_dst[ab+1] + v0.z*a_dst[ab+2] + v0.w*a_dst[ab+3]
             + v1.x*a_dst[32+ab] + v1.y*a_dst[32+ab+1] + v1.z*a_dst[32+ab+2] + v1.w*a_dst[32+ab+3];
    ps += __shfl_xor(ps, 1); ps += __shfl_xor(ps, 2); ps += __shfl_xor(ps, 4);
    pd += __shfl_xor(pd, 1); pd += __shfl_xor(pd, 2); pd += __shfl_xor(pd, 4);
    if (ok && cg == 0){ al_s[n] = ps; al_d[n] = pd; }
  }
}

// ---------------- layer-2 aggregation -> d_out, bf16 rows, 4x unrolled ----------------
__global__ __launch_bounds__(256) void k_agg2(const int* __restrict__ rowptr, const int* __restrict__ csr,
    const unsigned short* __restrict__ gb, const float* __restrict__ al_s, const float* __restrict__ al_d,
    const float* __restrict__ b2, float* __restrict__ out){
  int wid  = (blockIdx.x*256 + threadIdx.x) >> 6;   // node id
  int lane = threadIdx.x & 63;                      // channel
  if (wid >= NN) return;
  float ad = al_d[wid];
  int rs = rowptr[wid], re = rowptr[wid+1];
  float acc = 0.f, den = 0.f;
  int i = rs;
  for (; i + 4 <= re; i += 4){
    int s0 = csr[i], s1 = csr[i+1], s2 = csr[i+2], s3 = csr[i+3];
    float e0 = al_s[s0], e1 = al_s[s1], e2 = al_s[s2], e3 = al_s[s3];
    unsigned short u0 = gb[(size_t)s0*64 + lane];
    unsigned short u1 = gb[(size_t)s1*64 + lane];
    unsigned short u2 = gb[(size_t)s2*64 + lane];
    unsigned short u3 = gb[(size_t)s3*64 + lane];
    float ex0 = __expf(lrelu(e0 + ad));
    float ex1 = __expf(lrelu(e1 + ad));
    float ex2 = __expf(lrelu(e2 + ad));
    float ex3 = __expf(lrelu(e3 + ad));
    den += ex0 + ex1 + ex2 + ex3;
    acc += ex0*__uint_as_float((uint)u0 << 16) + ex1*__uint_as_float((uint)u1 << 16)
         + ex2*__uint_as_float((uint)u2 << 16) + ex3*__uint_as_float((uint)u3 << 16);
  }
  for (; i < re; ++i){
    int s = csr[i];
    float ex = __expf(lrelu(al_s[s] + ad));
    unsigned short u = gb[(size_t)s*64 + lane];
    den += ex;
    acc += ex*__uint_as_float((uint)u << 16);
  }
  out[(size_t)wid*64 + lane] = acc/(den + 1e-16f) + b2[lane];
}

extern "C" void kernel_launch(void* const* d_in, const int* in_sizes, int n_in,
                              void* d_out, int out_size, void* d_ws, size_t ws_size,
                              hipStream_t stream){
  const float* x   = (const float*)d_in[0];
  const int*   ei  = (const int*)d_in[1];
  const float* W1  = (const float*)d_in[2];
  const float* as1 = (const float*)d_in[3];
  const float* ad1 = (const float*)d_in[4];
  const float* b1  = (const float*)d_in[5];
  const float* W2  = (const float*)d_in[6];
  const float* as2 = (const float*)d_in[7];
  const float* ad2 = (const float*)d_in[8];
  const float* b2  = (const float*)d_in[9];
  float* out = (float*)d_out;
  (void)in_sizes; (void)n_in; (void)out_size; (void)ws_size;

  char* p = (char*)d_ws;
  size_t off = 0;
  auto alloc = [&](size_t bytes)->char*{
    char* r = p + off; off += (bytes + 255) & ~size_t(255); return r;
  };
  uint*  h1b   = (uint*)alloc((size_t)NN*64*4);     // bf16-packed [N][128]
  float* h2    = (float*)alloc((size_t)NN*128*4);
  uint*  gb    = (uint*)alloc((size_t)NN*32*4);     // bf16-packed [N][64]
  float* al1s  = (float*)alloc((size_t)NN*4*4);
  float* al1d  = (float*)alloc((size_t)NN*4*4);
  float* al2s  = (float*)alloc((size_t)NN*4);
  float* al2d  = (float*)alloc((size_t)NN*4);
  int*   deg   = (int*)alloc((size_t)NN*4);
  int*   rowptr= (int*)alloc((size_t)(NN+1)*4);
  int*   cursor= (int*)alloc((size_t)NN*4);
  int*   csr   = (int*)alloc((size_t)TE*4);
  int*   bsum  = (int*)alloc((size_t)SCAN_B*4);
  int*   boff  = (int*)alloc((size_t)SCAN_B*4);

  k_init_deg<<<SCAN_B, 256, 0, stream>>>(deg);
  k_hist<<<(EE+255)/256, 256, 0, stream>>>(ei, deg);
  k_bsum<<<SCAN_B, 256, 0, stream>>>(deg, bsum);
  k_bscan<<<1, 256, 0, stream>>>(bsum, boff);
  k_final<<<SCAN_B, 256, 0, stream>>>(deg, boff, rowptr, cursor);
  k_scatter<<<(TE+255)/256, 256, 0, stream>>>(ei, cursor, csr);
  k_gemm1<<<(NN+127)/128, 256, 0, stream>>>(x, W1, as1, ad1, h1b, al1s, al1d);
  k_agg1<<<(NN*64+255)/256, 256, 0, stream>>>(rowptr, csr, h1b, al1s, al1d, b1, h2);
  k_gemm2<<<(NN+127)/128, 256, 0, stream>>>(h2, W2, as2, ad2, gb, al2s, al2d);
  k_agg2<<<(NN*64+255)/256, 256, 0, stream>>>(rowptr, csr, (const unsigned short*)gb, al2s, al2d, b2, out);
}

// Round 4
// 182.435 us; speedup vs baseline: 2.5986x; 1.3372x over previous
//
#include <hip/hip_runtime.h>

#define NN 50000
#define EE 800000
#define TE (EE + NN)     // total edges including self loops
#define NB 196           // dst buckets of 256 nodes
#define CHUNK 2048       // edges per bucketize block
#define NBLK ((EE + CHUNK - 1) / CHUNK)   // 391
#define CAP 6144         // max edges per bucket (mean 4096, sd 64 -> +32 sigma)

typedef unsigned int uint;
typedef unsigned short ushort;

__device__ __forceinline__ float lrelu(float v){ return v > 0.f ? v : 0.2f*v; }
// round-to-nearest-even fp32 -> bf16 (top 16 bits), packed pair (lo=a, hi=b)
__device__ __forceinline__ uint pack_bf16(float a, float b){
  uint ua = __float_as_uint(a), ub = __float_as_uint(b);
  ua = (ua + 0x7FFFu + ((ua >> 16) & 1u)) >> 16;
  ub = (ub + 0x7FFFu + ((ub >> 16) & 1u)) & 0xFFFF0000u;
  return ua | ub;
}
__device__ __forceinline__ float bf_lo(uint u){ return __uint_as_float(u << 16); }
__device__ __forceinline__ float bf_hi(uint u){ return __uint_as_float(u & 0xFFFF0000u); }

// ---------------- CSR build (bucketed, no per-edge global atomics) ----------------
__global__ __launch_bounds__(256) void k_zero(int* __restrict__ bcnt){
  int t = threadIdx.x;
  if (t < NB) bcnt[t] = 0;
}

// per-block LDS histogram of dst>>8, flush once per bucket per block
__global__ __launch_bounds__(256) void k_bcount(const int* __restrict__ ei, int* __restrict__ bcnt){
  __shared__ int h[NB];
  int t = threadIdx.x;
  if (t < NB) h[t] = 0;
  __syncthreads();
  int base = blockIdx.x * CHUNK;
  int end = base + CHUNK; if (end > EE) end = EE;
  for (int i = base + t; i < end; i += 256)
    atomicAdd(&h[ei[EE + i] >> 8], 1);
  __syncthreads();
  if (t < NB && h[t]) atomicAdd(&bcnt[t], h[t]);
}

// 1-block exclusive scan of bucket counts -> ebase (pristine) + ecur (cursor)
__global__ __launch_bounds__(256) void k_bscan2(const int* __restrict__ bcnt,
                                                int* __restrict__ ebase, int* __restrict__ ecur){
  __shared__ int s[256];
  int t = threadIdx.x;
  int v = (t < NB) ? bcnt[t] : 0;
  s[t] = v;
  __syncthreads();
  for (int off = 1; off < 256; off <<= 1){
    int add = (t >= off) ? s[t-off] : 0;
    __syncthreads();
    s[t] += add;
    __syncthreads();
  }
  if (t < NB){ int ex = s[t] - v; ebase[t] = ex; ecur[t] = ex; }
}

// scatter edges into bucket-contiguous ebuf with per-(block,bucket) runs, coalesced writes
__global__ __launch_bounds__(256) void k_bucketize(const int* __restrict__ ei,
                                                   int* __restrict__ ecur, uint* __restrict__ ebuf){
  __shared__ int h[NB];          // per-block bucket counts, then reused as excl offsets
  __shared__ int sc[256];        // scan scratch
  __shared__ int gdelta[NB];     // global_base - local_base per bucket
  __shared__ uint P[CHUNK];      // packed edges, locally bucket-sorted
  __shared__ int  A[CHUNK];      // final global address per sorted slot
  int t = threadIdx.x;
  if (t < NB) h[t] = 0;
  __syncthreads();
  int base = blockIdx.x * CHUNK;
  int end = base + CHUNK; if (end > EE) end = EE;
  int bc = end - base;
  int be[8]; int re[8]; uint pe[8];
  #pragma unroll
  for (int q = 0; q < 8; ++q){
    int i = base + t + q*256;
    be[q] = -1;
    if (i < end){
      int s_ = ei[i], d_ = ei[EE + i];
      pe[q] = ((uint)d_ << 16) | (uint)s_;
      int bb = d_ >> 8;
      be[q] = bb;
      re[q] = atomicAdd(&h[bb], 1);
    }
  }
  __syncthreads();
  int v = (t < NB) ? h[t] : 0;
  sc[t] = v;
  __syncthreads();
  for (int off = 1; off < 256; off <<= 1){
    int add = (t >= off) ? sc[t-off] : 0;
    __syncthreads();
    sc[t] += add;
    __syncthreads();
  }
  if (t < NB){
    int lofs = sc[t] - v;                       // exclusive local base
    int g = v ? atomicAdd(&ecur[t], v) : 0;     // one global atomic per (block,bucket)
    gdelta[t] = g - lofs;
    h[t] = lofs;                                // h now holds local excl offsets
  }
  __syncthreads();
  #pragma unroll
  for (int q = 0; q < 8; ++q) if (be[q] >= 0){
    int j = h[be[q]] + re[q];
    P[j] = pe[q];
    A[j] = gdelta[be[q]] + j;
  }
  __syncthreads();
  for (int j = t; j < bc; j += 256) ebuf[A[j]] = P[j];   // consecutive j -> consecutive addr per run
}

// one block per bucket: local counting sort by dst_local -> rowptr + ushort csr (+self loops)
__global__ __launch_bounds__(256) void k_csr(const int* __restrict__ bcnt, const int* __restrict__ ebase,
                                             const uint* __restrict__ ebuf,
                                             int* __restrict__ rowptr, ushort* __restrict__ csr){
  __shared__ uint  sbuf[CAP];    // 24 KB
  __shared__ ushort rnk[CAP];    // 12 KB
  __shared__ int h[256];
  __shared__ int sc[256];
  int b = blockIdx.x, t = threadIdx.x;
  int nd0 = b * 256;
  int ncnt = NN - nd0; if (ncnt > 256) ncnt = 256;
  int cnt = bcnt[b]; if (cnt > CAP) cnt = CAP;
  int e0 = ebase[b];
  int cb = e0 + nd0;             // csr base: nd0 self-loops precede this bucket
  h[t] = (t < ncnt) ? 1 : 0;     // rank 0 reserved for self loop
  for (int j = t; j < cnt; j += 256) sbuf[j] = ebuf[e0 + j];
  __syncthreads();
  for (int j = t; j < cnt; j += 256){
    int local = (sbuf[j] >> 16) & 255;
    rnk[j] = (ushort)atomicAdd(&h[local], 1);
  }
  __syncthreads();
  int v = h[t];
  sc[t] = v;
  __syncthreads();
  for (int off = 1; off < 256; off <<= 1){
    int add = (t >= off) ? sc[t-off] : 0;
    __syncthreads();
    sc[t] += add;
    __syncthreads();
  }
  h[t] = sc[t] - v;              // exclusive per-node offsets
  __syncthreads();
  if (t < ncnt){
    int rp = cb + h[t];
    rowptr[nd0 + t] = rp;
    csr[rp] = (ushort)(nd0 + t);             // self loop at rank 0
  }
  if (b == NB-1 && t == 0) rowptr[NN] = TE;
  for (int j = t; j < cnt; j += 256){
    uint p = sbuf[j];
    int local = (p >> 16) & 255;
    csr[cb + h[local] + (int)rnk[j]] = (ushort)(p & 0xFFFFu);
  }
}

// ---------------- GEMM1: h1 = x @ W1 (+ fused attention dots), bf16 output ----------------
__global__ __launch_bounds__(256) void k_gemm1(const float* __restrict__ x, const float* __restrict__ W,
    const float* __restrict__ a_src, const float* __restrict__ a_dst,
    uint* __restrict__ h1b, float* __restrict__ al_s, float* __restrict__ al_d){
  __shared__ float Ws[64*128];      // 32 KB (one K-half)
  __shared__ float xs[128*68];      // 34 KB, stride 68
  int tid = threadIdx.x;
  int row0 = blockIdx.x * 128;
  int rg = tid >> 3;                // 0..31
  int cg = tid & 7;                 // 0..7
  float acc[64];
  #pragma unroll
  for (int i = 0; i < 64; ++i) acc[i] = 0.f;
  const float4* W4 = (const float4*)W;
  const float4* x4 = (const float4*)x;
  float4* Ws4 = (float4*)Ws;

  for (int kh = 0; kh < 2; ++kh){
    if (kh) __syncthreads();
    #pragma unroll
    for (int f0 = 0; f0 < 2048; f0 += 256){
      int f = f0 + tid;
      Ws4[f] = W4[kh*2048 + f];
    }
    #pragma unroll
    for (int f0 = 0; f0 < 2048; f0 += 256){
      int f = f0 + tid;
      int row = f >> 4, kq = f & 15;
      float4 v = make_float4(0.f,0.f,0.f,0.f);
      if (row0 + row < NN) v = x4[(size_t)(row0+row)*32 + kh*16 + kq];
      *(float4*)(xs + row*68 + kq*4) = v;
    }
    __syncthreads();

    #pragma unroll 4
    for (int k = 0; k < 64; ++k){
      float xv0 = xs[(rg     )*68 + k];
      float xv1 = xs[(rg + 32)*68 + k];
      float xv2 = xs[(rg + 64)*68 + k];
      float xv3 = xs[(rg + 96)*68 + k];
      const float4* wr = (const float4*)(Ws + k*128);
      float4 w0 = wr[cg], w1 = wr[cg+8], w2 = wr[cg+16], w3 = wr[cg+24];
      #define FMA_ROW(jr, xv) \
        acc[jr*16+ 0] += xv*w0.x; acc[jr*16+ 1] += xv*w0.y; acc[jr*16+ 2] += xv*w0.z; acc[jr*16+ 3] += xv*w0.w; \
        acc[jr*16+ 4] += xv*w1.x; acc[jr*16+ 5] += xv*w1.y; acc[jr*16+ 6] += xv*w1.z; acc[jr*16+ 7] += xv*w1.w; \
        acc[jr*16+ 8] += xv*w2.x; acc[jr*16+ 9] += xv*w2.y; acc[jr*16+10] += xv*w2.z; acc[jr*16+11] += xv*w2.w; \
        acc[jr*16+12] += xv*w3.x; acc[jr*16+13] += xv*w3.y; acc[jr*16+14] += xv*w3.z; acc[jr*16+15] += xv*w3.w;
      FMA_ROW(0, xv0) FMA_ROW(1, xv1) FMA_ROW(2, xv2) FMA_ROW(3, xv3)
      #undef FMA_ROW
    }
  }

  #pragma unroll
  for (int jr = 0; jr < 4; ++jr){
    int n = row0 + rg + 32*jr;
    bool ok = (n < NN);
    uint* orow = h1b + (size_t)n*64;
    #pragma unroll
    for (int jc = 0; jc < 4; ++jc){
      float4 v = make_float4(acc[jr*16+jc*4], acc[jr*16+jc*4+1], acc[jr*16+jc*4+2], acc[jr*16+jc*4+3]);
      if (ok){
        uint2 pv = make_uint2(pack_bf16(v.x, v.y), pack_bf16(v.z, v.w));
        *(uint2*)(orow + jc*16 + cg*2) = pv;     // channels jc*32+cg*4 .. +3
      }
      int ab = jc*32 + cg*4;
      float ps = v.x*a_src[ab] + v.y*a_src[ab+1] + v.z*a_src[ab+2] + v.w*a_src[ab+3];
      float pd = v.x*a_dst[ab] + v.y*a_dst[ab+1] + v.z*a_dst[ab+2] + v.w*a_dst[ab+3];
      ps += __shfl_xor(ps, 1); ps += __shfl_xor(ps, 2); ps += __shfl_xor(ps, 4);
      pd += __shfl_xor(pd, 1); pd += __shfl_xor(pd, 2); pd += __shfl_xor(pd, 4);
      if (ok && cg == 0){ al_s[n*4 + jc] = ps; al_d[n*4 + jc] = pd; }
    }
  }
}

// ---------------- layer-1 aggregation (softmax + ELU), bf16 rows, 4x unrolled ----------------
__global__ __launch_bounds__(256) void k_agg1(const int* __restrict__ rowptr, const ushort* __restrict__ csr,
    const uint* __restrict__ h1b, const float* __restrict__ al_s, const float* __restrict__ al_d,
    const float* __restrict__ b1, float* __restrict__ h2){
  int wid  = (blockIdx.x*256 + threadIdx.x) >> 6;   // node id
  int lane = threadIdx.x & 63;
  if (wid >= NN) return;
  int h = lane >> 4;                  // channels (2*lane, 2*lane+1) share head
  float ad = al_d[wid*4 + h];
  int rs = rowptr[wid], re = rowptr[wid+1];
  float accx = 0.f, accy = 0.f, den = 0.f;
  int i = rs;
  for (; i + 4 <= re; i += 4){
    int s0 = csr[i], s1 = csr[i+1], s2 = csr[i+2], s3 = csr[i+3];
    float e0 = al_s[s0*4+h], e1 = al_s[s1*4+h], e2 = al_s[s2*4+h], e3 = al_s[s3*4+h];
    uint u0 = h1b[(size_t)s0*64 + lane];
    uint u1 = h1b[(size_t)s1*64 + lane];
    uint u2 = h1b[(size_t)s2*64 + lane];
    uint u3 = h1b[(size_t)s3*64 + lane];
    float ex0 = __expf(lrelu(e0 + ad));
    float ex1 = __expf(lrelu(e1 + ad));
    float ex2 = __expf(lrelu(e2 + ad));
    float ex3 = __expf(lrelu(e3 + ad));
    den  += ex0 + ex1 + ex2 + ex3;
    accx += ex0*bf_lo(u0) + ex1*bf_lo(u1) + ex2*bf_lo(u2) + ex3*bf_lo(u3);
    accy += ex0*bf_hi(u0) + ex1*bf_hi(u1) + ex2*bf_hi(u2) + ex3*bf_hi(u3);
  }
  for (; i < re; ++i){
    int s = csr[i];
    float ex = __expf(lrelu(al_s[s*4+h] + ad));
    uint u = h1b[(size_t)s*64 + lane];
    den += ex;
    accx += ex*bf_lo(u); accy += ex*bf_hi(u);
  }
  float inv = 1.f/(den + 1e-16f);
  float2 bb = *(const float2*)(b1 + lane*2);
  float o0 = accx*inv + bb.x;
  float o1 = accy*inv + bb.y;
  o0 = o0 > 0.f ? o0 : (__expf(o0) - 1.f);          // ELU fused
  o1 = o1 > 0.f ? o1 : (__expf(o1) - 1.f);
  *(float2*)(h2 + (size_t)wid*128 + lane*2) = make_float2(o0, o1);
}

// ---------------- GEMM2: g = h2 @ W2 (+ fused attention dots), bf16 output ----------------
__global__ __launch_bounds__(256) void k_gemm2(const float* __restrict__ h2, const float* __restrict__ W,
    const float* __restrict__ a_src, const float* __restrict__ a_dst,
    uint* __restrict__ gb, float* __restrict__ al_s, float* __restrict__ al_d){
  __shared__ float Ws[64*64];       // 16 KB
  __shared__ float xs[128*68];      // 34 KB
  int tid = threadIdx.x;
  int row0 = blockIdx.x * 128;
  int rg = tid >> 3;
  int cg = tid & 7;
  float acc[32];
  #pragma unroll
  for (int i = 0; i < 32; ++i) acc[i] = 0.f;
  const float4* W4 = (const float4*)W;
  const float4* x4 = (const float4*)h2;
  float4* Ws4 = (float4*)Ws;

  for (int kh = 0; kh < 2; ++kh){
    if (kh) __syncthreads();
    #pragma unroll
    for (int f0 = 0; f0 < 1024; f0 += 256){
      int f = f0 + tid;
      Ws4[f] = W4[kh*1024 + f];
    }
    #pragma unroll
    for (int f0 = 0; f0 < 2048; f0 += 256){
      int f = f0 + tid;
      int row = f >> 4, kq = f & 15;
      float4 v = make_float4(0.f,0.f,0.f,0.f);
      if (row0 + row < NN) v = x4[(size_t)(row0+row)*32 + kh*16 + kq];
      *(float4*)(xs + row*68 + kq*4) = v;
    }
    __syncthreads();

    #pragma unroll 4
    for (int k = 0; k < 64; ++k){
      float xv0 = xs[(rg     )*68 + k];
      float xv1 = xs[(rg + 32)*68 + k];
      float xv2 = xs[(rg + 64)*68 + k];
      float xv3 = xs[(rg + 96)*68 + k];
      const float4* wr = (const float4*)(Ws + k*64);
      float4 w0 = wr[cg], w1 = wr[cg+8];
      #define FMA_ROW2(jr, xv) \
        acc[jr*8+0] += xv*w0.x; acc[jr*8+1] += xv*w0.y; acc[jr*8+2] += xv*w0.z; acc[jr*8+3] += xv*w0.w; \
        acc[jr*8+4] += xv*w1.x; acc[jr*8+5] += xv*w1.y; acc[jr*8+6] += xv*w1.z; acc[jr*8+7] += xv*w1.w;
      FMA_ROW2(0, xv0) FMA_ROW2(1, xv1) FMA_ROW2(2, xv2) FMA_ROW2(3, xv3)
      #undef FMA_ROW2
    }
  }

  #pragma unroll
  for (int jr = 0; jr < 4; ++jr){
    int n = row0 + rg + 32*jr;
    bool ok = (n < NN);
    float4 v0 = make_float4(acc[jr*8+0], acc[jr*8+1], acc[jr*8+2], acc[jr*8+3]);
    float4 v1 = make_float4(acc[jr*8+4], acc[jr*8+5], acc[jr*8+6], acc[jr*8+7]);
    if (ok){
      uint* orow = gb + (size_t)n*32;
      *(uint2*)(orow + cg*2)      = make_uint2(pack_bf16(v0.x, v0.y), pack_bf16(v0.z, v0.w));
      *(uint2*)(orow + 16 + cg*2) = make_uint2(pack_bf16(v1.x, v1.y), pack_bf16(v1.z, v1.w));
    }
    int ab = cg*4;
    float ps = v0.x*a_src[ab] + v0.y*a_src[ab+1] + v0.z*a_src[ab+2] + v0.w*a_src[ab+3]
             + v1.x*a_src[32+ab] + v1.y*a_src[32+ab+1] + v1.z*a_src[32+ab+2] + v1.w*a_src[32+ab+3];
    float pd = v0.x*a_dst[ab] + v0.y*a_dst[ab+1] + v0.z*a_dst[ab+2] + v0.w*a_dst[ab+3]
             + v1.x*a_dst[32+ab] + v1.y*a_dst[32+ab+1] + v1.z*a_dst[32+ab+2] + v1.w*a_dst[32+ab+3];
    ps += __shfl_xor(ps, 1); ps += __shfl_xor(ps, 2); ps += __shfl_xor(ps, 4);
    pd += __shfl_xor(pd, 1); pd += __shfl_xor(pd, 2); pd += __shfl_xor(pd, 4);
    if (ok && cg == 0){ al_s[n] = ps; al_d[n] = pd; }
  }
}

// ---------------- layer-2 aggregation -> d_out, bf16 rows, 4x unrolled ----------------
__global__ __launch_bounds__(256) void k_agg2(const int* __restrict__ rowptr, const ushort* __restrict__ csr,
    const ushort* __restrict__ gb, const float* __restrict__ al_s, const float* __restrict__ al_d,
    const float* __restrict__ b2, float* __restrict__ out){
  int wid  = (blockIdx.x*256 + threadIdx.x) >> 6;   // node id
  int lane = threadIdx.x & 63;                      // channel
  if (wid >= NN) return;
  float ad = al_d[wid];
  int rs = rowptr[wid], re = rowptr[wid+1];
  float acc = 0.f, den = 0.f;
  int i = rs;
  for (; i + 4 <= re; i += 4){
    int s0 = csr[i], s1 = csr[i+1], s2 = csr[i+2], s3 = csr[i+3];
    float e0 = al_s[s0], e1 = al_s[s1], e2 = al_s[s2], e3 = al_s[s3];
    ushort u0 = gb[(size_t)s0*64 + lane];
    ushort u1 = gb[(size_t)s1*64 + lane];
    ushort u2 = gb[(size_t)s2*64 + lane];
    ushort u3 = gb[(size_t)s3*64 + lane];
    float ex0 = __expf(lrelu(e0 + ad));
    float ex1 = __expf(lrelu(e1 + ad));
    float ex2 = __expf(lrelu(e2 + ad));
    float ex3 = __expf(lrelu(e3 + ad));
    den += ex0 + ex1 + ex2 + ex3;
    acc += ex0*__uint_as_float((uint)u0 << 16) + ex1*__uint_as_float((uint)u1 << 16)
         + ex2*__uint_as_float((uint)u2 << 16) + ex3*__uint_as_float((uint)u3 << 16);
  }
  for (; i < re; ++i){
    int s = csr[i];
    float ex = __expf(lrelu(al_s[s] + ad));
    ushort u = gb[(size_t)s*64 + lane];
    den += ex;
    acc += ex*__uint_as_float((uint)u << 16);
  }
  out[(size_t)wid*64 + lane] = acc/(den + 1e-16f) + b2[lane];
}

extern "C" void kernel_launch(void* const* d_in, const int* in_sizes, int n_in,
                              void* d_out, int out_size, void* d_ws, size_t ws_size,
                              hipStream_t stream){
  const float* x   = (const float*)d_in[0];
  const int*   ei  = (const int*)d_in[1];
  const float* W1  = (const float*)d_in[2];
  const float* as1 = (const float*)d_in[3];
  const float* ad1 = (const float*)d_in[4];
  const float* b1  = (const float*)d_in[5];
  const float* W2  = (const float*)d_in[6];
  const float* as2 = (const float*)d_in[7];
  const float* ad2 = (const float*)d_in[8];
  const float* b2  = (const float*)d_in[9];
  float* out = (float*)d_out;
  (void)in_sizes; (void)n_in; (void)out_size; (void)ws_size;

  char* p = (char*)d_ws;
  size_t off = 0;
  auto alloc = [&](size_t bytes)->char*{
    char* r = p + off; off += (bytes + 255) & ~size_t(255); return r;
  };
  uint*  h1b   = (uint*)alloc((size_t)NN*64*4);     // bf16-packed [N][128]
  float* h2    = (float*)alloc((size_t)NN*128*4);
  uint*  gb    = (uint*)alloc((size_t)NN*32*4);     // bf16-packed [N][64]
  float* al1s  = (float*)alloc((size_t)NN*4*4);
  float* al1d  = (float*)alloc((size_t)NN*4*4);
  float* al2s  = (float*)alloc((size_t)NN*4);
  float* al2d  = (float*)alloc((size_t)NN*4);
  int*   rowptr= (int*)alloc((size_t)(NN+1)*4);
  ushort* csr  = (ushort*)alloc((size_t)TE*2);
  uint*  ebuf  = (uint*)alloc((size_t)EE*4);
  int*   bcnt  = (int*)alloc((size_t)NB*4);
  int*   ebase = (int*)alloc((size_t)NB*4);
  int*   ecur  = (int*)alloc((size_t)NB*4);

  k_zero<<<1, 256, 0, stream>>>(bcnt);
  k_bcount<<<NBLK, 256, 0, stream>>>(ei, bcnt);
  k_bscan2<<<1, 256, 0, stream>>>(bcnt, ebase, ecur);
  k_bucketize<<<NBLK, 256, 0, stream>>>(ei, ecur, ebuf);
  k_csr<<<NB, 256, 0, stream>>>(bcnt, ebase, ebuf, rowptr, csr);
  k_gemm1<<<(NN+127)/128, 256, 0, stream>>>(x, W1, as1, ad1, h1b, al1s, al1d);
  k_agg1<<<(NN*64+255)/256, 256, 0, stream>>>(rowptr, csr, h1b, al1s, al1d, b1, h2);
  k_gemm2<<<(NN+127)/128, 256, 0, stream>>>(h2, W2, as2, ad2, gb, al2s, al2d);
  k_agg2<<<(NN*64+255)/256, 256, 0, stream>>>(rowptr, csr, (const ushort*)gb, al2s, al2d, b2, out);
}

// Round 5
// 174.488 us; speedup vs baseline: 2.7169x; 1.0455x over previous
//
#include <hip/hip_runtime.h>

#define NN 50000
#define EE 800000
#define TE (EE + NN)     // total edges including self loops
#define NB 196           // dst buckets of 256 nodes
#define CHUNK 2048       // edges per bucketize block
#define NBLK ((EE + CHUNK - 1) / CHUNK)   // 391
#define CAP 6144         // max edges per bucket (mean 4096, sd 64 -> +32 sigma)

typedef unsigned int uint;
typedef unsigned short ushort;

__device__ __forceinline__ float lrelu(float v){ return v > 0.f ? v : 0.2f*v; }
// round-to-nearest-even fp32 -> bf16 (top 16 bits), packed pair (lo=a, hi=b)
__device__ __forceinline__ uint pack_bf16(float a, float b){
  uint ua = __float_as_uint(a), ub = __float_as_uint(b);
  ua = (ua + 0x7FFFu + ((ua >> 16) & 1u)) >> 16;
  ub = (ub + 0x7FFFu + ((ub >> 16) & 1u)) & 0xFFFF0000u;
  return ua | ub;
}
__device__ __forceinline__ float bf_lo(uint u){ return __uint_as_float(u << 16); }
__device__ __forceinline__ float bf_hi(uint u){ return __uint_as_float(u & 0xFFFF0000u); }

// ---------------- CSR build (bucketed, no per-edge global atomics) ----------------
__global__ __launch_bounds__(256) void k_zero(int* __restrict__ bcnt){
  int t = threadIdx.x;
  if (t < NB) bcnt[t] = 0;
}

__global__ __launch_bounds__(256) void k_bcount(const int* __restrict__ ei, int* __restrict__ bcnt){
  __shared__ int h[NB];
  int t = threadIdx.x;
  if (t < NB) h[t] = 0;
  __syncthreads();
  int base = blockIdx.x * CHUNK;
  int end = base + CHUNK; if (end > EE) end = EE;
  for (int i = base + t; i < end; i += 256)
    atomicAdd(&h[ei[EE + i] >> 8], 1);
  __syncthreads();
  if (t < NB && h[t]) atomicAdd(&bcnt[t], h[t]);
}

__global__ __launch_bounds__(256) void k_bscan2(const int* __restrict__ bcnt,
                                                int* __restrict__ ebase, int* __restrict__ ecur){
  __shared__ int s[256];
  int t = threadIdx.x;
  int v = (t < NB) ? bcnt[t] : 0;
  s[t] = v;
  __syncthreads();
  for (int off = 1; off < 256; off <<= 1){
    int add = (t >= off) ? s[t-off] : 0;
    __syncthreads();
    s[t] += add;
    __syncthreads();
  }
  if (t < NB){ int ex = s[t] - v; ebase[t] = ex; ecur[t] = ex; }
}

__global__ __launch_bounds__(256) void k_bucketize(const int* __restrict__ ei,
                                                   int* __restrict__ ecur, uint* __restrict__ ebuf){
  __shared__ int h[NB];
  __shared__ int sc[256];
  __shared__ int gdelta[NB];
  __shared__ uint P[CHUNK];
  __shared__ int  A[CHUNK];
  int t = threadIdx.x;
  if (t < NB) h[t] = 0;
  __syncthreads();
  int base = blockIdx.x * CHUNK;
  int end = base + CHUNK; if (end > EE) end = EE;
  int bc = end - base;
  int be[8]; int re[8]; uint pe[8];
  #pragma unroll
  for (int q = 0; q < 8; ++q){
    int i = base + t + q*256;
    be[q] = -1;
    if (i < end){
      int s_ = ei[i], d_ = ei[EE + i];
      pe[q] = ((uint)d_ << 16) | (uint)s_;
      int bb = d_ >> 8;
      be[q] = bb;
      re[q] = atomicAdd(&h[bb], 1);
    }
  }
  __syncthreads();
  int v = (t < NB) ? h[t] : 0;
  sc[t] = v;
  __syncthreads();
  for (int off = 1; off < 256; off <<= 1){
    int add = (t >= off) ? sc[t-off] : 0;
    __syncthreads();
    sc[t] += add;
    __syncthreads();
  }
  if (t < NB){
    int lofs = sc[t] - v;
    int g = v ? atomicAdd(&ecur[t], v) : 0;
    gdelta[t] = g - lofs;
    h[t] = lofs;
  }
  __syncthreads();
  #pragma unroll
  for (int q = 0; q < 8; ++q) if (be[q] >= 0){
    int j = h[be[q]] + re[q];
    P[j] = pe[q];
    A[j] = gdelta[be[q]] + j;
  }
  __syncthreads();
  for (int j = t; j < bc; j += 256) ebuf[A[j]] = P[j];
}

__global__ __launch_bounds__(256) void k_csr(const int* __restrict__ bcnt, const int* __restrict__ ebase,
                                             const uint* __restrict__ ebuf,
                                             int* __restrict__ rowptr, ushort* __restrict__ csr){
  __shared__ uint  sbuf[CAP];
  __shared__ ushort rnk[CAP];
  __shared__ int h[256];
  __shared__ int sc[256];
  int b = blockIdx.x, t = threadIdx.x;
  int nd0 = b * 256;
  int ncnt = NN - nd0; if (ncnt > 256) ncnt = 256;
  int cnt = bcnt[b]; if (cnt > CAP) cnt = CAP;
  int e0 = ebase[b];
  int cb = e0 + nd0;
  h[t] = (t < ncnt) ? 1 : 0;
  for (int j = t; j < cnt; j += 256) sbuf[j] = ebuf[e0 + j];
  __syncthreads();
  for (int j = t; j < cnt; j += 256){
    int local = (sbuf[j] >> 16) & 255;
    rnk[j] = (ushort)atomicAdd(&h[local], 1);
  }
  __syncthreads();
  int v = h[t];
  sc[t] = v;
  __syncthreads();
  for (int off = 1; off < 256; off <<= 1){
    int add = (t >= off) ? sc[t-off] : 0;
    __syncthreads();
    sc[t] += add;
    __syncthreads();
  }
  h[t] = sc[t] - v;
  __syncthreads();
  if (t < ncnt){
    int rp = cb + h[t];
    rowptr[nd0 + t] = rp;
    csr[rp] = (ushort)(nd0 + t);
  }
  if (b == NB-1 && t == 0) rowptr[NN] = TE;
  for (int j = t; j < cnt; j += 256){
    uint p = sbuf[j];
    int local = (p >> 16) & 255;
    csr[cb + h[local] + (int)rnk[j]] = (ushort)(p & 0xFFFFu);
  }
}

// ---------------- GEMM1: h1 = x @ W1 (+ fused attention dots), bf16 output ----------------
__global__ __launch_bounds__(256) void k_gemm1(const float* __restrict__ x, const float* __restrict__ W,
    const float* __restrict__ a_src, const float* __restrict__ a_dst,
    uint* __restrict__ h1b, float* __restrict__ al_s, float* __restrict__ al_d){
  __shared__ float Ws[64*128];      // 32 KB (one K-half)
  __shared__ float xs[128*68];      // 34 KB, stride 68
  int tid = threadIdx.x;
  int row0 = blockIdx.x * 128;
  int rg = tid >> 3;                // 0..31
  int cg = tid & 7;                 // 0..7
  float acc[64];
  #pragma unroll
  for (int i = 0; i < 64; ++i) acc[i] = 0.f;
  const float4* W4 = (const float4*)W;
  const float4* x4 = (const float4*)x;
  float4* Ws4 = (float4*)Ws;

  for (int kh = 0; kh < 2; ++kh){
    if (kh) __syncthreads();
    #pragma unroll
    for (int f0 = 0; f0 < 2048; f0 += 256){
      int f = f0 + tid;
      Ws4[f] = W4[kh*2048 + f];
    }
    #pragma unroll
    for (int f0 = 0; f0 < 2048; f0 += 256){
      int f = f0 + tid;
      int row = f >> 4, kq = f & 15;
      float4 v = make_float4(0.f,0.f,0.f,0.f);
      if (row0 + row < NN) v = x4[(size_t)(row0+row)*32 + kh*16 + kq];
      *(float4*)(xs + row*68 + kq*4) = v;
    }
    __syncthreads();

    #pragma unroll 4
    for (int k = 0; k < 64; ++k){
      float xv0 = xs[(rg     )*68 + k];
      float xv1 = xs[(rg + 32)*68 + k];
      float xv2 = xs[(rg + 64)*68 + k];
      float xv3 = xs[(rg + 96)*68 + k];
      const float4* wr = (const float4*)(Ws + k*128);
      float4 w0 = wr[cg], w1 = wr[cg+8], w2 = wr[cg+16], w3 = wr[cg+24];
      #define FMA_ROW(jr, xv) \
        acc[jr*16+ 0] += xv*w0.x; acc[jr*16+ 1] += xv*w0.y; acc[jr*16+ 2] += xv*w0.z; acc[jr*16+ 3] += xv*w0.w; \
        acc[jr*16+ 4] += xv*w1.x; acc[jr*16+ 5] += xv*w1.y; acc[jr*16+ 6] += xv*w1.z; acc[jr*16+ 7] += xv*w1.w; \
        acc[jr*16+ 8] += xv*w2.x; acc[jr*16+ 9] += xv*w2.y; acc[jr*16+10] += xv*w2.z; acc[jr*16+11] += xv*w2.w; \
        acc[jr*16+12] += xv*w3.x; acc[jr*16+13] += xv*w3.y; acc[jr*16+14] += xv*w3.z; acc[jr*16+15] += xv*w3.w;
      FMA_ROW(0, xv0) FMA_ROW(1, xv1) FMA_ROW(2, xv2) FMA_ROW(3, xv3)
      #undef FMA_ROW
    }
  }

  #pragma unroll
  for (int jr = 0; jr < 4; ++jr){
    int n = row0 + rg + 32*jr;
    bool ok = (n < NN);
    uint* orow = h1b + (size_t)n*64;
    #pragma unroll
    for (int jc = 0; jc < 4; ++jc){
      float4 v = make_float4(acc[jr*16+jc*4], acc[jr*16+jc*4+1], acc[jr*16+jc*4+2], acc[jr*16+jc*4+3]);
      if (ok){
        uint2 pv = make_uint2(pack_bf16(v.x, v.y), pack_bf16(v.z, v.w));
        *(uint2*)(orow + jc*16 + cg*2) = pv;
      }
      int ab = jc*32 + cg*4;
      float ps = v.x*a_src[ab] + v.y*a_src[ab+1] + v.z*a_src[ab+2] + v.w*a_src[ab+3];
      float pd = v.x*a_dst[ab] + v.y*a_dst[ab+1] + v.z*a_dst[ab+2] + v.w*a_dst[ab+3];
      ps += __shfl_xor(ps, 1); ps += __shfl_xor(ps, 2); ps += __shfl_xor(ps, 4);
      pd += __shfl_xor(pd, 1); pd += __shfl_xor(pd, 2); pd += __shfl_xor(pd, 4);
      if (ok && cg == 0){ al_s[n*4 + jc] = ps; al_d[n*4 + jc] = pd; }
    }
  }
}

// ---------------- layer-1 aggregation: half-wave per edge, uint2 loads, bf16 out ----------------
__global__ __launch_bounds__(256) void k_agg1(const int* __restrict__ rowptr, const ushort* __restrict__ csr,
    const uint* __restrict__ h1b, const float* __restrict__ al_s, const float* __restrict__ al_d,
    const float* __restrict__ b1, uint* __restrict__ h2b){
  int wid  = (blockIdx.x*256 + threadIdx.x) >> 6;   // node id (1 wave per node)
  int lane = threadIdx.x & 63;
  if (wid >= NN) return;
  int half = lane >> 5;               // 0: even edges, 1: odd edges
  int li   = lane & 31;               // lane owns channels 4li..4li+3
  int h    = li >> 3;                 // head of those channels
  float ad = al_d[wid*4 + h];
  int rs = rowptr[wid], re = rowptr[wid+1];
  float a0 = 0.f, a1 = 0.f, a2 = 0.f, a3 = 0.f, den = 0.f;
  int i = rs + half;
  for (; i + 2 < re; i += 4){         // two edges per lane per iter
    int s0 = csr[i], s1 = csr[i+2];
    float e0 = al_s[s0*4 + h], e1 = al_s[s1*4 + h];
    uint2 u0 = *(const uint2*)(h1b + (size_t)s0*64 + li*2);
    uint2 u1 = *(const uint2*)(h1b + (size_t)s1*64 + li*2);
    float ex0 = __expf(lrelu(e0 + ad));
    float ex1 = __expf(lrelu(e1 + ad));
    den += ex0 + ex1;
    a0 += ex0*bf_lo(u0.x) + ex1*bf_lo(u1.x);
    a1 += ex0*bf_hi(u0.x) + ex1*bf_hi(u1.x);
    a2 += ex0*bf_lo(u0.y) + ex1*bf_lo(u1.y);
    a3 += ex0*bf_hi(u0.y) + ex1*bf_hi(u1.y);
  }
  for (; i < re; i += 2){
    int s0 = csr[i];
    float ex = __expf(lrelu(al_s[s0*4 + h] + ad));
    uint2 u = *(const uint2*)(h1b + (size_t)s0*64 + li*2);
    den += ex;
    a0 += ex*bf_lo(u.x); a1 += ex*bf_hi(u.x);
    a2 += ex*bf_lo(u.y); a3 += ex*bf_hi(u.y);
  }
  // combine halves (edge-parity split)
  den += __shfl_xor(den, 32);
  a0  += __shfl_xor(a0, 32);
  a1  += __shfl_xor(a1, 32);
  a2  += __shfl_xor(a2, 32);
  a3  += __shfl_xor(a3, 32);
  if (half == 0){
    float inv = 1.f/(den + 1e-16f);
    float4 bb = *(const float4*)(b1 + li*4);
    float o0 = a0*inv + bb.x, o1 = a1*inv + bb.y, o2 = a2*inv + bb.z, o3 = a3*inv + bb.w;
    o0 = o0 > 0.f ? o0 : (__expf(o0) - 1.f);        // ELU fused
    o1 = o1 > 0.f ? o1 : (__expf(o1) - 1.f);
    o2 = o2 > 0.f ? o2 : (__expf(o2) - 1.f);
    o3 = o3 > 0.f ? o3 : (__expf(o3) - 1.f);
    *(uint2*)(h2b + (size_t)wid*64 + li*2) = make_uint2(pack_bf16(o0,o1), pack_bf16(o2,o3));
  }
}

// ---------------- GEMM2: g = h2 @ W2 (+ fused attention dots), bf16 in/out ----------------
__global__ __launch_bounds__(256) void k_gemm2(const uint* __restrict__ h2b, const float* __restrict__ W,
    const float* __restrict__ a_src, const float* __restrict__ a_dst,
    uint* __restrict__ gb, float* __restrict__ al_s, float* __restrict__ al_d){
  __shared__ float Ws[64*64];       // 16 KB
  __shared__ float xs[128*68];      // 34 KB
  int tid = threadIdx.x;
  int row0 = blockIdx.x * 128;
  int rg = tid >> 3;
  int cg = tid & 7;
  float acc[32];
  #pragma unroll
  for (int i = 0; i < 32; ++i) acc[i] = 0.f;
  const float4* W4 = (const float4*)W;
  const uint4* x4 = (const uint4*)h2b;
  float4* Ws4 = (float4*)Ws;

  for (int kh = 0; kh < 2; ++kh){
    if (kh) __syncthreads();
    #pragma unroll
    for (int f0 = 0; f0 < 1024; f0 += 256){
      int f = f0 + tid;
      Ws4[f] = W4[kh*1024 + f];
    }
    #pragma unroll
    for (int f0 = 0; f0 < 1024; f0 += 256){
      int f = f0 + tid;
      int row = f >> 3, q = f & 7;            // 8 uint4 per row-half (32 uints = 64 floats)
      uint4 u = make_uint4(0,0,0,0);
      if (row0 + row < NN) u = x4[(size_t)(row0+row)*16 + kh*8 + q];
      float* xp = xs + row*68 + q*8;
      *(float4*)xp     = make_float4(bf_lo(u.x), bf_hi(u.x), bf_lo(u.y), bf_hi(u.y));
      *(float4*)(xp+4) = make_float4(bf_lo(u.z), bf_hi(u.z), bf_lo(u.w), bf_hi(u.w));
    }
    __syncthreads();

    #pragma unroll 4
    for (int k = 0; k < 64; ++k){
      float xv0 = xs[(rg     )*68 + k];
      float xv1 = xs[(rg + 32)*68 + k];
      float xv2 = xs[(rg + 64)*68 + k];
      float xv3 = xs[(rg + 96)*68 + k];
      const float4* wr = (const float4*)(Ws + k*64);
      float4 w0 = wr[cg], w1 = wr[cg+8];
      #define FMA_ROW2(jr, xv) \
        acc[jr*8+0] += xv*w0.x; acc[jr*8+1] += xv*w0.y; acc[jr*8+2] += xv*w0.z; acc[jr*8+3] += xv*w0.w; \
        acc[jr*8+4] += xv*w1.x; acc[jr*8+5] += xv*w1.y; acc[jr*8+6] += xv*w1.z; acc[jr*8+7] += xv*w1.w;
      FMA_ROW2(0, xv0) FMA_ROW2(1, xv1) FMA_ROW2(2, xv2) FMA_ROW2(3, xv3)
      #undef FMA_ROW2
    }
  }

  #pragma unroll
  for (int jr = 0; jr < 4; ++jr){
    int n = row0 + rg + 32*jr;
    bool ok = (n < NN);
    float4 v0 = make_float4(acc[jr*8+0], acc[jr*8+1], acc[jr*8+2], acc[jr*8+3]);
    float4 v1 = make_float4(acc[jr*8+4], acc[jr*8+5], acc[jr*8+6], acc[jr*8+7]);
    if (ok){
      uint* orow = gb + (size_t)n*32;
      *(uint2*)(orow + cg*2)      = make_uint2(pack_bf16(v0.x, v0.y), pack_bf16(v0.z, v0.w));
      *(uint2*)(orow + 16 + cg*2) = make_uint2(pack_bf16(v1.x, v1.y), pack_bf16(v1.z, v1.w));
    }
    int ab = cg*4;
    float ps = v0.x*a_src[ab] + v0.y*a_src[ab+1] + v0.z*a_src[ab+2] + v0.w*a_src[ab+3]
             + v1.x*a_src[32+ab] + v1.y*a_src[32+ab+1] + v1.z*a_src[32+ab+2] + v1.w*a_src[32+ab+3];
    float pd = v0.x*a_dst[ab] + v0.y*a_dst[ab+1] + v0.z*a_dst[ab+2] + v0.w*a_dst[ab+3]
             + v1.x*a_dst[32+ab] + v1.y*a_dst[32+ab+1] + v1.z*a_dst[32+ab+2] + v1.w*a_dst[32+ab+3];
    ps += __shfl_xor(ps, 1); ps += __shfl_xor(ps, 2); ps += __shfl_xor(ps, 4);
    pd += __shfl_xor(pd, 1); pd += __shfl_xor(pd, 2); pd += __shfl_xor(pd, 4);
    if (ok && cg == 0){ al_s[n] = ps; al_d[n] = pd; }
  }
}

// ---------------- layer-2 aggregation: half-wave per edge, uint loads -> d_out ----------------
__global__ __launch_bounds__(256) void k_agg2(const int* __restrict__ rowptr, const ushort* __restrict__ csr,
    const uint* __restrict__ gb, const float* __restrict__ al_s, const float* __restrict__ al_d,
    const float* __restrict__ b2, float* __restrict__ out){
  int wid  = (blockIdx.x*256 + threadIdx.x) >> 6;   // node id (1 wave per node)
  int lane = threadIdx.x & 63;
  if (wid >= NN) return;
  int half = lane >> 5;
  int li   = lane & 31;               // lane owns channels 2li, 2li+1
  float ad = al_d[wid];
  int rs = rowptr[wid], re = rowptr[wid+1];
  float a0 = 0.f, a1 = 0.f, den = 0.f;
  int i = rs + half;
  for (; i + 2 < re; i += 4){
    int s0 = csr[i], s1 = csr[i+2];
    float e0 = al_s[s0], e1 = al_s[s1];
    uint u0 = gb[(size_t)s0*32 + li];
    uint u1 = gb[(size_t)s1*32 + li];
    float ex0 = __expf(lrelu(e0 + ad));
    float ex1 = __expf(lrelu(e1 + ad));
    den += ex0 + ex1;
    a0 += ex0*bf_lo(u0) + ex1*bf_lo(u1);
    a1 += ex0*bf_hi(u0) + ex1*bf_hi(u1);
  }
  for (; i < re; i += 2){
    int s0 = csr[i];
    float ex = __expf(lrelu(al_s[s0] + ad));
    uint u = gb[(size_t)s0*32 + li];
    den += ex;
    a0 += ex*bf_lo(u); a1 += ex*bf_hi(u);
  }
  den += __shfl_xor(den, 32);
  a0  += __shfl_xor(a0, 32);
  a1  += __shfl_xor(a1, 32);
  if (half == 0){
    float inv = 1.f/(den + 1e-16f);
    float2 bb = *(const float2*)(b2 + li*2);
    *(float2*)(out + (size_t)wid*64 + li*2) = make_float2(a0*inv + bb.x, a1*inv + bb.y);
  }
}

extern "C" void kernel_launch(void* const* d_in, const int* in_sizes, int n_in,
                              void* d_out, int out_size, void* d_ws, size_t ws_size,
                              hipStream_t stream){
  const float* x   = (const float*)d_in[0];
  const int*   ei  = (const int*)d_in[1];
  const float* W1  = (const float*)d_in[2];
  const float* as1 = (const float*)d_in[3];
  const float* ad1 = (const float*)d_in[4];
  const float* b1  = (const float*)d_in[5];
  const float* W2  = (const float*)d_in[6];
  const float* as2 = (const float*)d_in[7];
  const float* ad2 = (const float*)d_in[8];
  const float* b2  = (const float*)d_in[9];
  float* out = (float*)d_out;
  (void)in_sizes; (void)n_in; (void)out_size; (void)ws_size;

  char* p = (char*)d_ws;
  size_t off = 0;
  auto alloc = [&](size_t bytes)->char*{
    char* r = p + off; off += (bytes + 255) & ~size_t(255); return r;
  };
  uint*  h1b   = (uint*)alloc((size_t)NN*64*4);     // bf16-packed [N][128]
  uint*  h2b   = (uint*)alloc((size_t)NN*64*4);     // bf16-packed [N][128]
  uint*  gb    = (uint*)alloc((size_t)NN*32*4);     // bf16-packed [N][64]
  float* al1s  = (float*)alloc((size_t)NN*4*4);
  float* al1d  = (float*)alloc((size_t)NN*4*4);
  float* al2s  = (float*)alloc((size_t)NN*4);
  float* al2d  = (float*)alloc((size_t)NN*4);
  int*   rowptr= (int*)alloc((size_t)(NN+1)*4);
  ushort* csr  = (ushort*)alloc((size_t)TE*2);
  uint*  ebuf  = (uint*)alloc((size_t)EE*4);
  int*   bcnt  = (int*)alloc((size_t)NB*4);
  int*   ebase = (int*)alloc((size_t)NB*4);
  int*   ecur  = (int*)alloc((size_t)NB*4);

  k_zero<<<1, 256, 0, stream>>>(bcnt);
  k_bcount<<<NBLK, 256, 0, stream>>>(ei, bcnt);
  k_bscan2<<<1, 256, 0, stream>>>(bcnt, ebase, ecur);
  k_bucketize<<<NBLK, 256, 0, stream>>>(ei, ecur, ebuf);
  k_csr<<<NB, 256, 0, stream>>>(bcnt, ebase, ebuf, rowptr, csr);
  k_gemm1<<<(NN+127)/128, 256, 0, stream>>>(x, W1, as1, ad1, h1b, al1s, al1d);
  k_agg1<<<(NN*64+255)/256, 256, 0, stream>>>(rowptr, csr, h1b, al1s, al1d, b1, h2b);
  k_gemm2<<<(NN+127)/128, 256, 0, stream>>>(h2b, W2, as2, ad2, gb, al2s, al2d);
  k_agg2<<<(NN*64+255)/256, 256, 0, stream>>>(rowptr, csr, gb, al2s, al2d, b2, out);
}